// Round 1
// baseline (201.472 us; speedup 1.0000x reference)
//
#include <hip/hip_runtime.h>

// DistMult decoder: out[e] = sigmoid( sum_d x[l,d] * R[et,d] * x[r,d] )
//
// R3 structure: temporal dim-split to make the gather table L2-resident.
//  R2 analysis: FETCH 231 MB = 48 MB compulsory streaming + ~183 MB random
//  128-B line fills from L3, because the 6.4 MB fp16 x-table does not fit
//  the 4 MiB per-XCD L2 (~18% miss on 8M row-gathers). Bound by random-line
//  miss service rate (~3 TB/s), not HBM streaming and not VALU (42%).
//
//  A) convert x (100k x 32 fp32) -> TWO half-tables in d_ws:
//       xhA[node][dims 0..15]  fp16, 3.2 MB
//       xhB[node][dims 16..31] fp16, 3.2 MB
//     Each fits per-XCD L2 (4 MiB) -> gathers become L2 hits.
//  B) pass 0: gather xhA halves, partial score -> out[e] (raw, fp32).
//     pass 1: gather xhB halves, out[e] = sigmoid(out[e] + s).
//     4 lanes/edge (4 dims each), 4-edge unroll per 4-lane group.
//     Streaming traffic (eidx/etype/partial) uses non-temporal hints so it
//     doesn't evict the hot table from L2.
// Accuracy: identical math to R2 (fp16 x, fp32 R, fp32 accumulate; partial
// staged in fp32 exactly) -> absmax unchanged ~0.0039.

typedef _Float16 half4 __attribute__((ext_vector_type(4)));
typedef int      iv4   __attribute__((ext_vector_type(4)));
typedef float    fv4   __attribute__((ext_vector_type(4)));

__global__ __launch_bounds__(256) void convert_split_kernel(
    const fv4* __restrict__ x,    // [nodes*8] float4 chunks (32 dims/node)
    half4*     __restrict__ xhA,  // [nodes*4] half4 (dims 0..15)
    half4*     __restrict__ xhB,  // [nodes*4] half4 (dims 16..31)
    int n4)
{
    int i = blockIdx.x * blockDim.x + threadIdx.x;
    if (i >= n4) return;
    fv4 v = x[i];
    half4 h;
    h.x = (_Float16)v.x; h.y = (_Float16)v.y;
    h.z = (_Float16)v.z; h.w = (_Float16)v.w;
    int node = i >> 3;
    int c    = i & 7;
    if (c < 4) xhA[node * 4 + c]       = h;
    else       xhB[node * 4 + (c - 4)] = h;
}

__device__ __forceinline__ float sigmoidf_fast(float s) {
    return __builtin_amdgcn_rcpf(1.0f + __expf(-s));
}

template <int PASS>
__global__ __launch_bounds__(256) void distmult_pass_kernel(
    const half4* __restrict__ xh,    // half-table for this pass: [nodes][4] half4
    const fv4*   __restrict__ R,     // [N_REL][8] float4 (full rows; use cols PASS*4..+3)
    const int*   __restrict__ eidx,  // [2, E]
    const int*   __restrict__ etype, // [E]
    float*       __restrict__ out,   // pass0: raw partial; pass1: final sigmoid
    int E)
{
    const int tid = blockIdx.x * blockDim.x + threadIdx.x;
    const int g   = tid >> 2;        // 4-lane group id
    const int d4  = tid & 3;         // which 4-dim chunk of this pass's 16 dims
    const int e0  = g << 2;          // first of this group's 4 edges
    if (e0 >= E) return;

    if (e0 + 4 <= E) {
        // Streaming loads: non-temporal so they don't evict the hot table.
        const iv4 l4 = __builtin_nontemporal_load((const iv4*)(eidx + e0));
        const iv4 r4 = __builtin_nontemporal_load((const iv4*)(eidx + E + e0));
        const iv4 t4 = __builtin_nontemporal_load((const iv4*)(etype + e0));

        fv4 prev = {};
        if (PASS == 1 && d4 == 0) {
            prev = *(const fv4*)(out + e0);   // issued early, latency overlaps gathers
        }

        // 12 independent gathers: 8x 8B half4 (L2-resident table) + 4x 16B R
        // (sorted etype -> L1-hot).
        const half4 a0 = xh[l4.x * 4 + d4];
        const half4 a1 = xh[l4.y * 4 + d4];
        const half4 a2 = xh[l4.z * 4 + d4];
        const half4 a3 = xh[l4.w * 4 + d4];
        const half4 b0 = xh[r4.x * 4 + d4];
        const half4 b1 = xh[r4.y * 4 + d4];
        const half4 b2 = xh[r4.z * 4 + d4];
        const half4 b3 = xh[r4.w * 4 + d4];
        const fv4 c0 = R[t4.x * 8 + PASS * 4 + d4];
        const fv4 c1 = R[t4.y * 8 + PASS * 4 + d4];
        const fv4 c2 = R[t4.z * 8 + PASS * 4 + d4];
        const fv4 c3 = R[t4.w * 8 + PASS * 4 + d4];

        float s0 = (float)a0.x * c0.x * (float)b0.x;
        s0 = fmaf((float)a0.y * c0.y, (float)b0.y, s0);
        s0 = fmaf((float)a0.z * c0.z, (float)b0.z, s0);
        s0 = fmaf((float)a0.w * c0.w, (float)b0.w, s0);
        float s1 = (float)a1.x * c1.x * (float)b1.x;
        s1 = fmaf((float)a1.y * c1.y, (float)b1.y, s1);
        s1 = fmaf((float)a1.z * c1.z, (float)b1.z, s1);
        s1 = fmaf((float)a1.w * c1.w, (float)b1.w, s1);
        float s2 = (float)a2.x * c2.x * (float)b2.x;
        s2 = fmaf((float)a2.y * c2.y, (float)b2.y, s2);
        s2 = fmaf((float)a2.z * c2.z, (float)b2.z, s2);
        s2 = fmaf((float)a2.w * c2.w, (float)b2.w, s2);
        float s3 = (float)a3.x * c3.x * (float)b3.x;
        s3 = fmaf((float)a3.y * c3.y, (float)b3.y, s3);
        s3 = fmaf((float)a3.z * c3.z, (float)b3.z, s3);
        s3 = fmaf((float)a3.w * c3.w, (float)b3.w, s3);

        // Reduce across the 4-lane group (each lane held 4 of 16 dims).
        s0 += __shfl_xor(s0, 1); s0 += __shfl_xor(s0, 2);
        s1 += __shfl_xor(s1, 1); s1 += __shfl_xor(s1, 2);
        s2 += __shfl_xor(s2, 1); s2 += __shfl_xor(s2, 2);
        s3 += __shfl_xor(s3, 1); s3 += __shfl_xor(s3, 2);

        if (d4 == 0) {
            fv4 o;
            if (PASS == 0) {
                o.x = s0; o.y = s1; o.z = s2; o.w = s3;
            } else {
                o.x = sigmoidf_fast(prev.x + s0);
                o.y = sigmoidf_fast(prev.y + s1);
                o.z = sigmoidf_fast(prev.z + s2);
                o.w = sigmoidf_fast(prev.w + s3);
            }
            __builtin_nontemporal_store(o, (fv4*)(out + e0));
        }
    } else {
        for (int e = e0; e < E; ++e) {
            const int l = eidx[e];
            const int r = eidx[E + e];
            const int t = etype[e];
            const half4 a = xh[l * 4 + d4];
            const half4 b = xh[r * 4 + d4];
            const fv4   c = R[t * 8 + PASS * 4 + d4];
            float s = (float)a.x * c.x * (float)b.x;
            s = fmaf((float)a.y * c.y, (float)b.y, s);
            s = fmaf((float)a.z * c.z, (float)b.z, s);
            s = fmaf((float)a.w * c.w, (float)b.w, s);
            s += __shfl_xor(s, 1); s += __shfl_xor(s, 2);
            if (d4 == 0) {
                if (PASS == 0) out[e] = s;
                else           out[e] = sigmoidf_fast(out[e] + s);
            }
        }
    }
}

extern "C" void kernel_launch(void* const* d_in, const int* in_sizes, int n_in,
                              void* d_out, int out_size, void* d_ws, size_t ws_size,
                              hipStream_t stream) {
    const float* x     = (const float*)d_in[0];
    const float* R     = (const float*)d_in[1];
    const int*   eidx  = (const int*)d_in[2];
    const int*   etype = (const int*)d_in[3];
    float*       out   = (float*)d_out;

    const int E     = in_sizes[3];        // 4,000,000 edges
    const int nelem = in_sizes[0];        // nodes * 32
    const int nodes = nelem / 32;
    const int n4    = nelem / 4;          // float4 chunks of x

    half4* xhA = (half4*)d_ws;                                   // 3.2 MB
    half4* xhB = (half4*)((char*)d_ws + (size_t)nodes * 32);     // 3.2 MB (16 dims * 2 B/node)

    convert_split_kernel<<<(n4 + 255) / 256, 256, 0, stream>>>(
        (const fv4*)x, xhA, xhB, n4);

    const long long groups  = ((long long)E + 3) / 4;
    const long long threads = groups * 4;
    const int block = 256;
    const int grid  = (int)((threads + block - 1) / block);

    distmult_pass_kernel<0><<<grid, block, 0, stream>>>(
        xhA, (const fv4*)R, eidx, etype, out, E);
    distmult_pass_kernel<1><<<grid, block, 0, stream>>>(
        xhB, (const fv4*)R, eidx, etype, out, E);
}

// Round 2
// 157.227 us; speedup vs baseline: 1.2814x; 1.2814x over previous
//
#include <hip/hip_runtime.h>

// DistMult decoder: out[e] = sigmoid( sum_d x[l,d] * R[et,d] * x[r,d] )
//
// R4 structure: single pass, widest-possible gathers.
//  R2/R3 counter evidence fits dur ~= 21cyc * (gather instrs) + 3.3cyc *
//  (unique lines) per CU, IDENTICAL in L2-hit (R3: FETCH 44MB) and L2-miss
//  (R2: FETCH 231MB) regimes -> bottleneck is the per-CU address/request
//  path, not cache residency. R3's dim-split doubled line requests (two
//  32-B touches per row) -> regression.
//  Floors: lines = 8M (one 64-B fp16 row per node-read), gather instrs =
//  500K (16 rows/instr at 16 B/lane). This kernel hits both:
//   - 4 lanes/edge; lane d4 loads half8 chunk d4 (16 B) of xl and of xr
//     -> full 64-B rows, 1 instr per row-read, 16 rows per wave-instr.
//   - R stays fp32 in d_in (2x float4 per lane; sorted etype -> L1-hot,
//     same-line across groups so near-zero beta cost). Keeps ws at the
//     proven 6.4 MB (x fp16 only).
//   - 4-edge unroll: 8 half8 gathers + 8 R loads in flight.
//   - 2x shfl_xor reduction, lane d4==0 writes float4 of sigmoids.
// Accuracy: identical precision to R2 (fp16 x, fp32 R, fp32 accumulate)
// -> absmax ~0.0039.

typedef _Float16 half4 __attribute__((ext_vector_type(4)));
typedef _Float16 half8 __attribute__((ext_vector_type(8)));
typedef int      iv4   __attribute__((ext_vector_type(4)));
typedef float    fv4   __attribute__((ext_vector_type(4)));

__global__ __launch_bounds__(256) void convert_x_kernel(
    const fv4* __restrict__ x, half4* __restrict__ xh, int n4)
{
    int i = blockIdx.x * blockDim.x + threadIdx.x;
    if (i >= n4) return;
    fv4 v = x[i];
    half4 h;
    h.x = (_Float16)v.x; h.y = (_Float16)v.y;
    h.z = (_Float16)v.z; h.w = (_Float16)v.w;
    xh[i] = h;
}

__device__ __forceinline__ float sigmoidf_fast(float s) {
    return __builtin_amdgcn_rcpf(1.0f + __expf(-s));
}

// 8-dim fp32 dot of fp16 a,b scaled by fp32 R chunks cl (dims 0-3), ch (4-7)
#define DOT8(a, b, cl, ch, s) do {                                   \
    s = (float)a[0] * cl.x * (float)b[0];                            \
    s = fmaf((float)a[1] * cl.y, (float)b[1], s);                    \
    s = fmaf((float)a[2] * cl.z, (float)b[2], s);                    \
    s = fmaf((float)a[3] * cl.w, (float)b[3], s);                    \
    s = fmaf((float)a[4] * ch.x, (float)b[4], s);                    \
    s = fmaf((float)a[5] * ch.y, (float)b[5], s);                    \
    s = fmaf((float)a[6] * ch.z, (float)b[6], s);                    \
    s = fmaf((float)a[7] * ch.w, (float)b[7], s);                    \
} while (0)

__global__ __launch_bounds__(256) void distmult_kernel(
    const half8* __restrict__ xh,    // [N_NODES][4] half8 (64 B rows, fp16)
    const fv4*   __restrict__ R,     // [N_REL][8] float4 (128 B rows, fp32)
    const int*   __restrict__ eidx,  // [2, E]
    const int*   __restrict__ etype, // [E]
    float*       __restrict__ out,   // [E]
    int E)
{
    const int tid = blockIdx.x * blockDim.x + threadIdx.x;
    const int g   = tid >> 2;        // 4-lane group id
    const int d4  = tid & 3;         // which 16-B chunk (8 dims) of the row
    const int e0  = g << 2;          // first of this group's 4 edges
    if (e0 >= E) return;

    if (e0 + 4 <= E) {
        // Streaming loads (non-temporal; don't pollute L2).
        const iv4 l4 = __builtin_nontemporal_load((const iv4*)(eidx + e0));
        const iv4 r4 = __builtin_nontemporal_load((const iv4*)(eidx + E + e0));
        const iv4 t4 = __builtin_nontemporal_load((const iv4*)(etype + e0));

        // 8 wide gathers (16 B/lane, 16 rows per wave-instruction) issued
        // before any dependent math.
        const half8 a0 = xh[l4.x * 4 + d4];
        const half8 a1 = xh[l4.y * 4 + d4];
        const half8 a2 = xh[l4.z * 4 + d4];
        const half8 a3 = xh[l4.w * 4 + d4];
        const half8 b0 = xh[r4.x * 4 + d4];
        const half8 b1 = xh[r4.y * 4 + d4];
        const half8 b2 = xh[r4.z * 4 + d4];
        const half8 b3 = xh[r4.w * 4 + d4];
        // R chunks (L1-hot via sorted etype): dims d4*8 .. d4*8+7
        const fv4 cl0 = R[t4.x * 8 + d4 * 2];
        const fv4 ch0 = R[t4.x * 8 + d4 * 2 + 1];
        const fv4 cl1 = R[t4.y * 8 + d4 * 2];
        const fv4 ch1 = R[t4.y * 8 + d4 * 2 + 1];
        const fv4 cl2 = R[t4.z * 8 + d4 * 2];
        const fv4 ch2 = R[t4.z * 8 + d4 * 2 + 1];
        const fv4 cl3 = R[t4.w * 8 + d4 * 2];
        const fv4 ch3 = R[t4.w * 8 + d4 * 2 + 1];

        float s0, s1, s2, s3;
        DOT8(a0, b0, cl0, ch0, s0);
        DOT8(a1, b1, cl1, ch1, s1);
        DOT8(a2, b2, cl2, ch2, s2);
        DOT8(a3, b3, cl3, ch3, s3);

        // Reduce across the 4-lane group (each lane held 8 of 32 dims).
        s0 += __shfl_xor(s0, 1); s0 += __shfl_xor(s0, 2);
        s1 += __shfl_xor(s1, 1); s1 += __shfl_xor(s1, 2);
        s2 += __shfl_xor(s2, 1); s2 += __shfl_xor(s2, 2);
        s3 += __shfl_xor(s3, 1); s3 += __shfl_xor(s3, 2);

        if (d4 == 0) {
            fv4 o;
            o.x = sigmoidf_fast(s0);
            o.y = sigmoidf_fast(s1);
            o.z = sigmoidf_fast(s2);
            o.w = sigmoidf_fast(s3);
            __builtin_nontemporal_store(o, (fv4*)(out + e0));
        }
    } else {
        for (int e = e0; e < E; ++e) {
            const int l = eidx[e];
            const int r = eidx[E + e];
            const int t = etype[e];
            const half8 a  = xh[l * 4 + d4];
            const half8 b  = xh[r * 4 + d4];
            const fv4   cl = R[t * 8 + d4 * 2];
            const fv4   ch = R[t * 8 + d4 * 2 + 1];
            float s;
            DOT8(a, b, cl, ch, s);
            s += __shfl_xor(s, 1); s += __shfl_xor(s, 2);
            if (d4 == 0) out[e] = sigmoidf_fast(s);
        }
    }
}

extern "C" void kernel_launch(void* const* d_in, const int* in_sizes, int n_in,
                              void* d_out, int out_size, void* d_ws, size_t ws_size,
                              hipStream_t stream) {
    const float* x     = (const float*)d_in[0];
    const float* R     = (const float*)d_in[1];
    const int*   eidx  = (const int*)d_in[2];
    const int*   etype = (const int*)d_in[3];
    float*       out   = (float*)d_out;

    const int E   = in_sizes[3];          // 4,000,000 edges
    const int n4  = in_sizes[0] / 4;      // x element count / 4 (float4 units)
    half4* xh = (half4*)d_ws;             // 6.4 MB fp16 copy of x (proven size)

    convert_x_kernel<<<(n4 + 255) / 256, 256, 0, stream>>>(
        (const fv4*)x, xh, n4);

    const long long groups  = ((long long)E + 3) / 4;
    const long long threads = groups * 4;
    const int block = 256;
    const int grid  = (int)((threads + block - 1) / block);

    distmult_kernel<<<grid, block, 0, stream>>>(
        (const half8*)d_ws, (const fv4*)R, eidx, etype, out, E);
}

// Round 3
// 156.858 us; speedup vs baseline: 1.2844x; 1.0024x over previous
//
#include <hip/hip_runtime.h>

// DistMult decoder: out[e] = sigmoid( sum_d x[l,d] * R[et,d] * x[r,d] )
//
// R5 structure: R4 + fp16 R rows -> minimum VMEM instruction budget.
//  Counter model (R2/R3/R4 fit): dur tracks per-CU VMEM *instruction* count
//  (divergent gathers ~21 cyc each); bytes/row and L2 residency are
//  irrelevant (R3: FETCH 44MB vs R4: 210MB, same speed per instr budget).
//  R4 (69us) vs R3-pass (60us) differ ONLY in 8-vs-4 R-load instrs/wave.
//  This kernel: 16 VMEM instrs/wave = the measured floor geometry:
//   - 4 lanes/edge; lane d4 loads half8 chunk (16 B) of xl and xr rows
//     -> full 64-B fp16 rows, 16 rows per wave-instruction (8 instrs).
//   - R converted to fp16 rows (964 x 64 B = 61.7 KB in ws, after xh);
//     one half8 per lane per edge -> 4 R instrs/wave (L1-hot, sorted etype).
//   - 3 nontemporal streaming loads + 1 store.
//  Fallback: if ws_size can't fit Rh, use fp32 R (R4 path, proven).
// Accuracy: fp16 on x and R, fp32 accumulate. R is glorot-small (~0.25 std);
// fp16 R adds 2^-11 relative -> absmax ~0.004-0.005.

typedef _Float16 half4 __attribute__((ext_vector_type(4)));
typedef _Float16 half8 __attribute__((ext_vector_type(8)));
typedef int      iv4   __attribute__((ext_vector_type(4)));
typedef float    fv4   __attribute__((ext_vector_type(4)));

__global__ __launch_bounds__(256) void convert_kernel(
    const fv4* __restrict__ x, half4* __restrict__ xh, int n4,
    const fv4* __restrict__ R, half4* __restrict__ Rh, int nR4)
{
    int i = blockIdx.x * blockDim.x + threadIdx.x;
    if (i < n4) {
        fv4 v = x[i];
        half4 h;
        h.x = (_Float16)v.x; h.y = (_Float16)v.y;
        h.z = (_Float16)v.z; h.w = (_Float16)v.w;
        xh[i] = h;
    } else if (i < n4 + nR4) {
        int j = i - n4;
        fv4 v = R[j];
        half4 h;
        h.x = (_Float16)v.x; h.y = (_Float16)v.y;
        h.z = (_Float16)v.z; h.w = (_Float16)v.w;
        Rh[j] = h;
    }
}

__device__ __forceinline__ float sigmoidf_fast(float s) {
    return __builtin_amdgcn_rcpf(1.0f + __expf(-s));
}

// 8-dim fp32 dot: fp16 a,b scaled by fp16 R chunk c
#define DOT8H(a, b, c, s) do {                                       \
    s = (float)a[0] * (float)c[0] * (float)b[0];                     \
    s = fmaf((float)a[1] * (float)c[1], (float)b[1], s);             \
    s = fmaf((float)a[2] * (float)c[2], (float)b[2], s);             \
    s = fmaf((float)a[3] * (float)c[3], (float)b[3], s);             \
    s = fmaf((float)a[4] * (float)c[4], (float)b[4], s);             \
    s = fmaf((float)a[5] * (float)c[5], (float)b[5], s);             \
    s = fmaf((float)a[6] * (float)c[6], (float)b[6], s);             \
    s = fmaf((float)a[7] * (float)c[7], (float)b[7], s);             \
} while (0)

// 8-dim fp32 dot: fp16 a,b scaled by fp32 R chunks cl (dims 0-3), ch (4-7)
#define DOT8F(a, b, cl, ch, s) do {                                  \
    s = (float)a[0] * cl.x * (float)b[0];                            \
    s = fmaf((float)a[1] * cl.y, (float)b[1], s);                    \
    s = fmaf((float)a[2] * cl.z, (float)b[2], s);                    \
    s = fmaf((float)a[3] * cl.w, (float)b[3], s);                    \
    s = fmaf((float)a[4] * ch.x, (float)b[4], s);                    \
    s = fmaf((float)a[5] * ch.y, (float)b[5], s);                    \
    s = fmaf((float)a[6] * ch.z, (float)b[6], s);                    \
    s = fmaf((float)a[7] * ch.w, (float)b[7], s);                    \
} while (0)

template <bool RF16>
__global__ __launch_bounds__(256) void distmult_kernel(
    const half8* __restrict__ xh,    // [N_NODES][4] half8 (64 B rows, fp16)
    const half8* __restrict__ Rh,    // [N_REL][4] half8 (64 B rows, fp16) if RF16
    const fv4*   __restrict__ Rf,    // [N_REL][8] float4 (fp32) fallback
    const int*   __restrict__ eidx,  // [2, E]
    const int*   __restrict__ etype, // [E]
    float*       __restrict__ out,   // [E]
    int E)
{
    const int tid = blockIdx.x * blockDim.x + threadIdx.x;
    const int g   = tid >> 2;        // 4-lane group id
    const int d4  = tid & 3;         // which 16-B chunk (8 dims) of the row
    const int e0  = g << 2;          // first of this group's 4 edges
    if (e0 >= E) return;

    if (e0 + 4 <= E) {
        // Streaming loads (non-temporal; don't pollute L2).
        const iv4 l4 = __builtin_nontemporal_load((const iv4*)(eidx + e0));
        const iv4 r4 = __builtin_nontemporal_load((const iv4*)(eidx + E + e0));
        const iv4 t4 = __builtin_nontemporal_load((const iv4*)(etype + e0));

        // 8 wide gathers (16 B/lane, 16 rows per wave-instruction).
        const half8 a0 = xh[l4.x * 4 + d4];
        const half8 a1 = xh[l4.y * 4 + d4];
        const half8 a2 = xh[l4.z * 4 + d4];
        const half8 a3 = xh[l4.w * 4 + d4];
        const half8 b0 = xh[r4.x * 4 + d4];
        const half8 b1 = xh[r4.y * 4 + d4];
        const half8 b2 = xh[r4.z * 4 + d4];
        const half8 b3 = xh[r4.w * 4 + d4];

        float s0, s1, s2, s3;
        if (RF16) {
            // 4 R instrs/wave (L1-hot via sorted etype)
            const half8 c0 = Rh[t4.x * 4 + d4];
            const half8 c1 = Rh[t4.y * 4 + d4];
            const half8 c2 = Rh[t4.z * 4 + d4];
            const half8 c3 = Rh[t4.w * 4 + d4];
            DOT8H(a0, b0, c0, s0);
            DOT8H(a1, b1, c1, s1);
            DOT8H(a2, b2, c2, s2);
            DOT8H(a3, b3, c3, s3);
        } else {
            const fv4 cl0 = Rf[t4.x * 8 + d4 * 2];
            const fv4 ch0 = Rf[t4.x * 8 + d4 * 2 + 1];
            const fv4 cl1 = Rf[t4.y * 8 + d4 * 2];
            const fv4 ch1 = Rf[t4.y * 8 + d4 * 2 + 1];
            const fv4 cl2 = Rf[t4.z * 8 + d4 * 2];
            const fv4 ch2 = Rf[t4.z * 8 + d4 * 2 + 1];
            const fv4 cl3 = Rf[t4.w * 8 + d4 * 2];
            const fv4 ch3 = Rf[t4.w * 8 + d4 * 2 + 1];
            DOT8F(a0, b0, cl0, ch0, s0);
            DOT8F(a1, b1, cl1, ch1, s1);
            DOT8F(a2, b2, cl2, ch2, s2);
            DOT8F(a3, b3, cl3, ch3, s3);
        }

        // Reduce across the 4-lane group (each lane held 8 of 32 dims).
        s0 += __shfl_xor(s0, 1); s0 += __shfl_xor(s0, 2);
        s1 += __shfl_xor(s1, 1); s1 += __shfl_xor(s1, 2);
        s2 += __shfl_xor(s2, 1); s2 += __shfl_xor(s2, 2);
        s3 += __shfl_xor(s3, 1); s3 += __shfl_xor(s3, 2);

        if (d4 == 0) {
            fv4 o;
            o.x = sigmoidf_fast(s0);
            o.y = sigmoidf_fast(s1);
            o.z = sigmoidf_fast(s2);
            o.w = sigmoidf_fast(s3);
            __builtin_nontemporal_store(o, (fv4*)(out + e0));
        }
    } else {
        for (int e = e0; e < E; ++e) {
            const int l = eidx[e];
            const int r = eidx[E + e];
            const int t = etype[e];
            const half8 a = xh[l * 4 + d4];
            const half8 b = xh[r * 4 + d4];
            float s;
            if (RF16) {
                const half8 c = Rh[t * 4 + d4];
                DOT8H(a, b, c, s);
            } else {
                const fv4 cl = Rf[t * 8 + d4 * 2];
                const fv4 ch = Rf[t * 8 + d4 * 2 + 1];
                DOT8F(a, b, cl, ch, s);
            }
            s += __shfl_xor(s, 1); s += __shfl_xor(s, 2);
            if (d4 == 0) out[e] = sigmoidf_fast(s);
        }
    }
}

extern "C" void kernel_launch(void* const* d_in, const int* in_sizes, int n_in,
                              void* d_out, int out_size, void* d_ws, size_t ws_size,
                              hipStream_t stream) {
    const float* x     = (const float*)d_in[0];
    const float* R     = (const float*)d_in[1];
    const int*   eidx  = (const int*)d_in[2];
    const int*   etype = (const int*)d_in[3];
    float*       out   = (float*)d_out;

    const int E     = in_sizes[3];          // 4,000,000 edges
    const int nelem = in_sizes[0];          // nodes * 32
    const int nodes = nelem / 32;
    const int nrel  = in_sizes[1] / 32;     // 964 relations
    const int n4    = nelem / 4;            // float4 chunks of x
    const int nR4   = in_sizes[1] / 4;      // float4 chunks of R

    half4* xh = (half4*)d_ws;                                  // 6.4 MB
    half4* Rh = (half4*)((char*)d_ws + (size_t)nodes * 64);    // 61.7 KB

    const bool rf16 =
        ws_size >= (size_t)nodes * 64 + (size_t)nrel * 64;

    const int convN = n4 + (rf16 ? nR4 : 0);
    convert_kernel<<<(convN + 255) / 256, 256, 0, stream>>>(
        (const fv4*)x, xh, n4, (const fv4*)R, Rh, rf16 ? nR4 : 0);

    const long long groups  = ((long long)E + 3) / 4;
    const long long threads = groups * 4;
    const int block = 256;
    const int grid  = (int)((threads + block - 1) / block);

    if (rf16) {
        distmult_kernel<true><<<grid, block, 0, stream>>>(
            (const half8*)xh, (const half8*)Rh, (const fv4*)R,
            eidx, etype, out, E);
    } else {
        distmult_kernel<false><<<grid, block, 0, stream>>>(
            (const half8*)xh, (const half8*)Rh, (const fv4*)R,
            eidx, etype, out, E);
    }
}